// Round 16
// baseline (195.249 us; speedup 1.0000x reference)
//
#include <hip/hip_runtime.h>
#include <math.h>

constexpr int NN   = 100000;   // nodes
constexpr int DIM  = 128;
constexpr int NE   = 3200000;  // edges
constexpr int NCLS = 40;
constexpr float EPSF = 1e-7f;

constexpr int BSH  = 9;                      // 512 cols per coarse bucket
constexpr int BSZ  = 1 << BSH;
constexpr int NBKT = (NN + BSZ - 1) >> BSH;  // 196
constexpr int CAP  = 18432;                  // bucket capacity
constexpr int AEPB = 4096;                   // edges per binA block
constexpr int ABLK = (NE + AEPB - 1) / AEPB; // 782

typedef __attribute__((ext_vector_type(8))) short bf16x8;
typedef __attribute__((ext_vector_type(8))) unsigned short u16x8;
typedef __attribute__((ext_vector_type(4))) float f32x4;

__device__ __forceinline__ unsigned short f2bf(float f) {
    unsigned u = __builtin_bit_cast(unsigned, f);
    unsigned r = u + 0x7FFFu + ((u >> 16) & 1u);
    return (unsigned short)(r >> 16);
}
__device__ __forceinline__ float bf2f(unsigned short b) {
    return __builtin_bit_cast(float, (unsigned)b << 16);
}

// ---- pass A: coarse-bucket partition with LDS shuffle, coalesced run writes
__global__ __launch_bounds__(256) void binA_kernel(const int* __restrict__ row,
                                                   const int* __restrict__ col,
                                                   int* __restrict__ gcur,
                                                   unsigned* __restrict__ pairs) {
    __shared__ int hist[256];
    __shared__ int lofx[256];
    __shared__ int gbase[256];
    __shared__ unsigned sortedw[AEPB];
    __shared__ int dstg[AEPB];

    int t = threadIdx.x;
    int e0 = blockIdx.x * AEPB;
    int cnt = min(AEPB, NE - e0);

    hist[t] = 0;
    __syncthreads();
    for (int k = t; k < cnt; k += 256) atomicAdd(&hist[col[e0 + k] >> BSH], 1);
    __syncthreads();

    int h = hist[t];
    if (t < NBKT && h > 0) gbase[t] = atomicAdd(&gcur[t], h);
    lofx[t] = h;
    __syncthreads();
    for (int d = 1; d < 256; d <<= 1) {
        int o = (t >= d) ? lofx[t - d] : 0;
        __syncthreads();
        lofx[t] += o;
        __syncthreads();
    }
    int excl = lofx[t] - h;
    lofx[t] = excl;
    hist[t] = excl;
    __syncthreads();

    for (int k = t; k < cnt; k += 256) {
        int c = col[e0 + k], r = row[e0 + k];
        int b = c >> BSH;
        int pos = atomicAdd(&hist[b], 1);
        sortedw[pos] = ((unsigned)(c & (BSZ - 1)) << 17) | (unsigned)r;
        dstg[pos] = b * CAP + gbase[b] + (pos - lofx[b]);
    }
    __syncthreads();
    for (int k = t; k < cnt; k += 256) pairs[dstg[k]] = sortedw[k];
}

// ---- bucket-base exclusive scan (196 values, one block) --------------------
__global__ __launch_bounds__(256) void bscan_kernel(const int* __restrict__ gcur,
                                                    int* __restrict__ bbase) {
    __shared__ int sc[256];
    int t = threadIdx.x;
    int v = (t < NBKT) ? gcur[t] : 0;
    sc[t] = v;
    __syncthreads();
    for (int d = 1; d < 256; d <<= 1) {
        int o = (t >= d) ? sc[t - d] : 0;
        __syncthreads();
        sc[t] += o;
        __syncthreads();
    }
    if (t < NBKT) bbase[t] = sc[t] - v;
}

// ---- pass B: per-bucket counting sort in LDS; writes offs + coalesced ebuf -
__global__ __launch_bounds__(1024) void binB_kernel(const int* __restrict__ gcur,
                                                    const int* __restrict__ bbase,
                                                    const unsigned* __restrict__ pairs,
                                                    int* __restrict__ ebuf,
                                                    int* __restrict__ offs) {
    __shared__ unsigned in[CAP];
    __shared__ int srow[CAP];
    __shared__ int hist[512];
    __shared__ int sc[1024];

    int t = threadIdx.x;
    int b = blockIdx.x;
    int cnt = gcur[b];
    int base = bbase[b];
    const unsigned* pb = pairs + (size_t)b * CAP;

    for (int i = t; i < cnt; i += 1024) in[i] = pb[i];
    if (t < 512) hist[t] = 0;
    __syncthreads();
    for (int i = t; i < cnt; i += 1024) atomicAdd(&hist[in[i] >> 17], 1);
    __syncthreads();

    int v = (t < 512) ? hist[t] : 0;
    sc[t] = v;
    __syncthreads();
    for (int d = 1; d < 1024; d <<= 1) {
        int o = (t >= d) ? sc[t - d] : 0;
        __syncthreads();
        sc[t] += o;
        __syncthreads();
    }
    int excl = sc[t] - v;
    if (t < 512) {
        int c = (b << BSH) + t;
        if (c <= NN) offs[c] = base + excl;
        hist[t] = excl;
    }
    __syncthreads();
    for (int i = t; i < cnt; i += 1024) {
        unsigned w = in[i];
        int pos = atomicAdd(&hist[w >> 17], 1);
        srow[pos] = (int)(w & 0x1FFFFu);
    }
    __syncthreads();
    for (int i = t; i < cnt; i += 1024) ebuf[base + i] = srow[i];
}

// ---- wpack: W[384][40] f32 -> hi/lo bf16 B-fragments in MFMA lane order ----
__global__ __launch_bounds__(256) void wpack_kernel(const float* __restrict__ W,
                                                    unsigned short* __restrict__ wbf) {
    int idx = blockIdx.x * 256 + threadIdx.x;
    if (idx >= 12 * 3 * 2 * 64 * 8) return;
    int j    = idx & 7;
    int lane = (idx >> 3) & 63;
    int hl   = (idx >> 9) & 1;
    int rest = idx >> 10;          // kc*3 + t
    int t    = rest % 3;
    int kc   = rest / 3;
    int k = kc * 32 + 8 * (lane >> 4) + j;
    int c = 16 * t + (lane & 15);
    float w = (c < NCLS) ? W[k * NCLS + c] : 0.f;
    unsigned short hi = f2bf(w);
    wbf[idx] = (hl == 0) ? hi : f2bf(w - bf2f(hi));
}

// ---------------- h = concat(xE, logH, logS) @ W ; g = h * dinv -------------
// Output now goes to 3 class-planes (p0:0-15, p1:16-31, p2:32-39) so each
// gather pass has an L2-resident (<=3.2 MB) table.
__global__ __launch_bounds__(256) void h_kernel(
    const float* __restrict__ xE, const float* __restrict__ xH,
    const float* __restrict__ xS, const unsigned short* __restrict__ wbf,
    const int* __restrict__ offs,
    unsigned short* __restrict__ p0, unsigned short* __restrict__ p1,
    unsigned short* __restrict__ p2) {

    __shared__ float4 t4[64 * 32];   // 32 KB; data slot s of row r at s^(r&7)
    __shared__ float dl[64];

    int t = threadIdx.x;
    int lane = t & 63;
    int wv = t >> 6;                 // wave id 0..3
    int n0 = blockIdx.x * 64;
    int r  = lane & 15;              // A row / C col
    int kq = lane >> 4;              // k-quarter
    int arow = 16 * wv + r;          // this lane's A row in the 64-node tile

    if (t < 64 && n0 + t < NN) {
        int d = offs[n0 + t + 1] - offs[n0 + t];
        dl[t] = rsqrtf((float)(d + 1));    // +1 self loop
    }

    f32x4 acc0 = {0.f, 0.f, 0.f, 0.f};
    f32x4 acc1 = acc0, acc2 = acc0;

    const bf16x8* wfr = reinterpret_cast<const bf16x8*>(wbf);

    for (int m = 0; m < 3; ++m) {
        const float* xb = (m == 0) ? xE : (m == 1) ? xH : xS;
        __syncthreads();   // previous phase's tile reads (and dl write) done
#pragma unroll
        for (int p = 0; p < 8; ++p) {
            int f4i = p * 256 + t;          // 0..2047
            int row  = f4i >> 5;
            int slot = f4i & 31;
            int gr = n0 + row;
            float4 v = make_float4(0.f, 0.f, 0.f, 0.f);
            if (gr < NN)
                v = *reinterpret_cast<const float4*>(
                    xb + (size_t)gr * DIM + slot * 4);
            t4[row * 32 + (slot ^ (row & 7))] = v;
        }
        __syncthreads();

        float scm = 1.f;
        if (m > 0) {
            float x0 = t4[arow * 32 + (r & 7)].x;   // data slot 0 of this row
            if (m == 1) {
                scm = acoshf(fmaxf(x0, 1.f)) * rsqrtf(fmaxf(x0 * x0 - 1.f, EPSF));
            } else {
                float cc = fminf(fmaxf(x0, -1.f), 1.f);
                scm = acosf(cc) * rsqrtf(fmaxf(1.f - x0 * x0, EPSF));
            }
        }

#pragma unroll
        for (int kc4 = 0; kc4 < 4; ++kc4) {
            int slot = kc4 * 8 + kq * 2;
            float4 f0 = t4[arow * 32 + (slot ^ (r & 7))];
            float4 f1 = t4[arow * 32 + ((slot + 1) ^ (r & 7))];
            float a[8] = {f0.x, f0.y, f0.z, f0.w, f1.x, f1.y, f1.z, f1.w};
            if (m > 0 && kc4 == 0 && kq == 0) a[0] = 0.f;   // logmap zeroes k=0

            bf16x8 ah, al;
#pragma unroll
            for (int j = 0; j < 8; ++j) {
                float av = a[j] * scm;
                unsigned short hbits = f2bf(av);
                ah[j] = (short)hbits;
                al[j] = (short)f2bf(av - bf2f(hbits));
            }

            int kc = m * 4 + kc4;
            const bf16x8* wb = wfr + (size_t)(kc * 3) * 2 * 64;
            bf16x8 bh0 = wb[0 * 128 + 0 * 64 + lane];
            bf16x8 bl0 = wb[0 * 128 + 1 * 64 + lane];
            bf16x8 bh1 = wb[1 * 128 + 0 * 64 + lane];
            bf16x8 bl1 = wb[1 * 128 + 1 * 64 + lane];
            bf16x8 bh2 = wb[2 * 128 + 0 * 64 + lane];
            bf16x8 bl2 = wb[2 * 128 + 1 * 64 + lane];

            acc0 = __builtin_amdgcn_mfma_f32_16x16x32_bf16(ah, bh0, acc0, 0, 0, 0);
            acc0 = __builtin_amdgcn_mfma_f32_16x16x32_bf16(al, bh0, acc0, 0, 0, 0);
            acc0 = __builtin_amdgcn_mfma_f32_16x16x32_bf16(ah, bl0, acc0, 0, 0, 0);
            acc1 = __builtin_amdgcn_mfma_f32_16x16x32_bf16(ah, bh1, acc1, 0, 0, 0);
            acc1 = __builtin_amdgcn_mfma_f32_16x16x32_bf16(al, bh1, acc1, 0, 0, 0);
            acc1 = __builtin_amdgcn_mfma_f32_16x16x32_bf16(ah, bl1, acc1, 0, 0, 0);
            acc2 = __builtin_amdgcn_mfma_f32_16x16x32_bf16(ah, bh2, acc2, 0, 0, 0);
            acc2 = __builtin_amdgcn_mfma_f32_16x16x32_bf16(al, bh2, acc2, 0, 0, 0);
            acc2 = __builtin_amdgcn_mfma_f32_16x16x32_bf16(ah, bl2, acc2, 0, 0, 0);
        }
    }

    // C/D: node = n0 + 16wv + 4*kq + i ; class = 16t + r   [m89 layout]
#pragma unroll
    for (int i = 0; i < 4; ++i) {
        int nl = 16 * wv + 4 * kq + i;
        int n = n0 + nl;
        if (n < NN) {
            float di = dl[nl];
            p0[(size_t)n * 16 + r] = f2bf(acc0[i] * di);
            p1[(size_t)n * 16 + r] = f2bf(acc1[i] * di);
            if (r < 8)
                p2[(size_t)n * 8 + r] = f2bf(acc2[i] * di);
        }
    }
}

// ------ gather over a 16-class plane (32 B rows, 2 threads/node) ------------
__global__ __launch_bounds__(256) void gather16_kernel(
    const int* __restrict__ offs, const int* __restrict__ ebuf,
    const unsigned short* __restrict__ plane, float* __restrict__ out,
    int cbase) {
    int t = blockIdx.x * blockDim.x + threadIdx.x;
    if (t >= NN * 2) return;
    int n = t >> 1, half = t & 1;

    const u16x8* gb = reinterpret_cast<const u16x8*>(plane) + half;
    int s = offs[n], e = offs[n + 1];
    float dinv = rsqrtf((float)(e - s + 1));

    u16x8 sv = gb[n * 2];            // self loop (dinv[n] folded in g)
    float a0[8], a1[8], a2[8], a3[8];
#pragma unroll
    for (int k = 0; k < 8; ++k) {
        a0[k] = bf2f(sv[k]); a1[k] = 0.f; a2[k] = 0.f; a3[k] = 0.f;
    }

    int j = s;
    for (; j + 3 < e; j += 4) {
        int r0 = ebuf[j], r1 = ebuf[j + 1], r2 = ebuf[j + 2], r3 = ebuf[j + 3];
        u16x8 v0 = gb[r0 * 2];
        u16x8 v1 = gb[r1 * 2];
        u16x8 v2 = gb[r2 * 2];
        u16x8 v3 = gb[r3 * 2];
#pragma unroll
        for (int k = 0; k < 8; ++k) {
            a0[k] += bf2f(v0[k]); a1[k] += bf2f(v1[k]);
            a2[k] += bf2f(v2[k]); a3[k] += bf2f(v3[k]);
        }
    }
    for (; j < e; ++j) {
        u16x8 v = gb[ebuf[j] * 2];
#pragma unroll
        for (int k = 0; k < 8; ++k) a0[k] += bf2f(v[k]);
    }

    float* on = out + (size_t)n * NCLS + cbase + half * 8;
    float4 o0, o1;
    o0.x = (a0[0] + a1[0] + a2[0] + a3[0]) * dinv;
    o0.y = (a0[1] + a1[1] + a2[1] + a3[1]) * dinv;
    o0.z = (a0[2] + a1[2] + a2[2] + a3[2]) * dinv;
    o0.w = (a0[3] + a1[3] + a2[3] + a3[3]) * dinv;
    o1.x = (a0[4] + a1[4] + a2[4] + a3[4]) * dinv;
    o1.y = (a0[5] + a1[5] + a2[5] + a3[5]) * dinv;
    o1.z = (a0[6] + a1[6] + a2[6] + a3[6]) * dinv;
    o1.w = (a0[7] + a1[7] + a2[7] + a3[7]) * dinv;
    *reinterpret_cast<float4*>(on)     = o0;
    *reinterpret_cast<float4*>(on + 4) = o1;
}

// ------ gather over the 8-class plane (16 B rows, 1 thread/node) ------------
__global__ __launch_bounds__(256) void gather8_kernel(
    const int* __restrict__ offs, const int* __restrict__ ebuf,
    const unsigned short* __restrict__ plane, float* __restrict__ out) {
    int n = blockIdx.x * blockDim.x + threadIdx.x;
    if (n >= NN) return;

    const u16x8* gb = reinterpret_cast<const u16x8*>(plane);
    int s = offs[n], e = offs[n + 1];
    float dinv = rsqrtf((float)(e - s + 1));

    u16x8 sv = gb[n];                // self loop
    float a0[8], a1[8], a2[8], a3[8];
#pragma unroll
    for (int k = 0; k < 8; ++k) {
        a0[k] = bf2f(sv[k]); a1[k] = 0.f; a2[k] = 0.f; a3[k] = 0.f;
    }

    int j = s;
    for (; j + 3 < e; j += 4) {
        int r0 = ebuf[j], r1 = ebuf[j + 1], r2 = ebuf[j + 2], r3 = ebuf[j + 3];
        u16x8 v0 = gb[r0];
        u16x8 v1 = gb[r1];
        u16x8 v2 = gb[r2];
        u16x8 v3 = gb[r3];
#pragma unroll
        for (int k = 0; k < 8; ++k) {
            a0[k] += bf2f(v0[k]); a1[k] += bf2f(v1[k]);
            a2[k] += bf2f(v2[k]); a3[k] += bf2f(v3[k]);
        }
    }
    for (; j < e; ++j) {
        u16x8 v = gb[ebuf[j]];
#pragma unroll
        for (int k = 0; k < 8; ++k) a0[k] += bf2f(v[k]);
    }

    float* on = out + (size_t)n * NCLS + 32;
    float4 o0, o1;
    o0.x = (a0[0] + a1[0] + a2[0] + a3[0]) * dinv;
    o0.y = (a0[1] + a1[1] + a2[1] + a3[1]) * dinv;
    o0.z = (a0[2] + a1[2] + a2[2] + a3[2]) * dinv;
    o0.w = (a0[3] + a1[3] + a2[3] + a3[3]) * dinv;
    o1.x = (a0[4] + a1[4] + a2[4] + a3[4]) * dinv;
    o1.y = (a0[5] + a1[5] + a2[5] + a3[5]) * dinv;
    o1.z = (a0[6] + a1[6] + a2[6] + a3[6]) * dinv;
    o1.w = (a0[7] + a1[7] + a2[7] + a3[7]) * dinv;
    *reinterpret_cast<float4*>(on)     = o0;
    *reinterpret_cast<float4*>(on + 4) = o1;
}

extern "C" void kernel_launch(void* const* d_in, const int* in_sizes, int n_in,
                              void* d_out, int out_size, void* d_ws, size_t ws_size,
                              hipStream_t stream) {
    const float* xE = (const float*)d_in[0];
    const float* xH = (const float*)d_in[1];
    const float* xS = (const float*)d_in[2];
    const float* W  = (const float*)d_in[3];
    const int*   ei = (const int*)d_in[4];
    const int* row = ei;            // edge_index[0]
    const int* col = ei + NE;       // edge_index[1]
    float* out = (float*)d_out;

    auto pad = [](size_t x) { return (x + 255) & ~(size_t)255; };
    char* p = (char*)d_ws;
    int* gcur  = (int*)p;               p += pad((size_t)NBKT * 4);
    int* bbase = (int*)p;               p += pad((size_t)NBKT * 4);
    int* offs  = (int*)p;               p += pad((size_t)(NN + 1) * 4);
    int* ebuf  = (int*)p;               p += pad((size_t)NE * 4);
    // pairs (NBKT*CAP*4 = 14.45 MB) aliases the g-planes (8 MB total): pairs
    // is dead after binB; planes are written by h afterwards.
    unsigned* pairs = (unsigned*)p;
    unsigned short* p0 = (unsigned short*)p;                 // 3.2 MB
    unsigned short* p1 = p0 + (size_t)NN * 16;               // 3.2 MB
    unsigned short* p2 = p1 + (size_t)NN * 16;               // 1.6 MB
    p += pad((size_t)NBKT * CAP * 4);
    unsigned short* wbf = (unsigned short*)p;                // 147456 B

    hipMemsetAsync(gcur, 0, (size_t)NBKT * 4, stream);

    wpack_kernel<<<(12 * 3 * 2 * 64 * 8 + 255) / 256, 256, 0, stream>>>(W, wbf);
    binA_kernel<<<ABLK, 256, 0, stream>>>(row, col, gcur, pairs);
    bscan_kernel<<<1, 256, 0, stream>>>(gcur, bbase);
    binB_kernel<<<NBKT, 1024, 0, stream>>>(gcur, bbase, pairs, ebuf, offs);
    h_kernel<<<(NN + 63) / 64, 256, 0, stream>>>(xE, xH, xS, wbf, offs, p0, p1, p2);
    gather16_kernel<<<(NN * 2 + 255) / 256, 256, 0, stream>>>(offs, ebuf, p0, out, 0);
    gather16_kernel<<<(NN * 2 + 255) / 256, 256, 0, stream>>>(offs, ebuf, p1, out, 16);
    gather8_kernel<<<(NN + 255) / 256, 256, 0, stream>>>(offs, ebuf, p2, out);
}

// Round 17
// 163.919 us; speedup vs baseline: 1.1911x; 1.1911x over previous
//
#include <hip/hip_runtime.h>
#include <math.h>

constexpr int NN   = 100000;   // nodes
constexpr int DIM  = 128;
constexpr int NE   = 3200000;  // edges
constexpr int NCLS = 40;
constexpr float EPSF = 1e-7f;

constexpr int BSH  = 9;                      // 512 cols per coarse bucket
constexpr int BSZ  = 1 << BSH;
constexpr int NBKT = (NN + BSZ - 1) >> BSH;  // 196
constexpr int CAP  = 18432;                  // bucket capacity
constexpr int AEPB = 4096;                   // edges per binA block
constexpr int ABLK = (NE + AEPB - 1) / AEPB; // 782

constexpr int GSTR = 64;                     // g row stride in halfwords (128 B)

typedef __attribute__((ext_vector_type(8))) short bf16x8;
typedef __attribute__((ext_vector_type(8))) unsigned short u16x8;
typedef __attribute__((ext_vector_type(4))) float f32x4;

__device__ __forceinline__ unsigned short f2bf(float f) {
    unsigned u = __builtin_bit_cast(unsigned, f);
    unsigned r = u + 0x7FFFu + ((u >> 16) & 1u);
    return (unsigned short)(r >> 16);
}
__device__ __forceinline__ float bf2f(unsigned short b) {
    return __builtin_bit_cast(float, (unsigned)b << 16);
}

// ---- pass A: coarse-bucket partition with LDS shuffle, coalesced run writes
__global__ __launch_bounds__(256) void binA_kernel(const int* __restrict__ row,
                                                   const int* __restrict__ col,
                                                   int* __restrict__ gcur,
                                                   unsigned* __restrict__ pairs) {
    __shared__ int hist[256];
    __shared__ int lofx[256];
    __shared__ int gbase[256];
    __shared__ unsigned sortedw[AEPB];
    __shared__ int dstg[AEPB];

    int t = threadIdx.x;
    int e0 = blockIdx.x * AEPB;
    int cnt = min(AEPB, NE - e0);

    hist[t] = 0;
    __syncthreads();
    for (int k = t; k < cnt; k += 256) atomicAdd(&hist[col[e0 + k] >> BSH], 1);
    __syncthreads();

    int h = hist[t];
    if (t < NBKT && h > 0) gbase[t] = atomicAdd(&gcur[t], h);
    lofx[t] = h;
    __syncthreads();
    for (int d = 1; d < 256; d <<= 1) {
        int o = (t >= d) ? lofx[t - d] : 0;
        __syncthreads();
        lofx[t] += o;
        __syncthreads();
    }
    int excl = lofx[t] - h;
    lofx[t] = excl;
    hist[t] = excl;
    __syncthreads();

    for (int k = t; k < cnt; k += 256) {
        int c = col[e0 + k], r = row[e0 + k];
        int b = c >> BSH;
        int pos = atomicAdd(&hist[b], 1);
        sortedw[pos] = ((unsigned)(c & (BSZ - 1)) << 17) | (unsigned)r;
        dstg[pos] = b * CAP + gbase[b] + (pos - lofx[b]);
    }
    __syncthreads();
    for (int k = t; k < cnt; k += 256) pairs[dstg[k]] = sortedw[k];
}

// ---- bucket-base exclusive scan (196 values, one block) --------------------
__global__ __launch_bounds__(256) void bscan_kernel(const int* __restrict__ gcur,
                                                    int* __restrict__ bbase) {
    __shared__ int sc[256];
    int t = threadIdx.x;
    int v = (t < NBKT) ? gcur[t] : 0;
    sc[t] = v;
    __syncthreads();
    for (int d = 1; d < 256; d <<= 1) {
        int o = (t >= d) ? sc[t - d] : 0;
        __syncthreads();
        sc[t] += o;
        __syncthreads();
    }
    if (t < NBKT) bbase[t] = sc[t] - v;
}

// ---- pass B: per-bucket counting sort in LDS; writes offs + coalesced ebuf -
__global__ __launch_bounds__(1024) void binB_kernel(const int* __restrict__ gcur,
                                                    const int* __restrict__ bbase,
                                                    const unsigned* __restrict__ pairs,
                                                    int* __restrict__ ebuf,
                                                    int* __restrict__ offs) {
    __shared__ unsigned in[CAP];
    __shared__ int srow[CAP];
    __shared__ int hist[512];
    __shared__ int sc[1024];

    int t = threadIdx.x;
    int b = blockIdx.x;
    int cnt = gcur[b];
    int base = bbase[b];
    const unsigned* pb = pairs + (size_t)b * CAP;

    for (int i = t; i < cnt; i += 1024) in[i] = pb[i];
    if (t < 512) hist[t] = 0;
    __syncthreads();
    for (int i = t; i < cnt; i += 1024) atomicAdd(&hist[in[i] >> 17], 1);
    __syncthreads();

    int v = (t < 512) ? hist[t] : 0;
    sc[t] = v;
    __syncthreads();
    for (int d = 1; d < 1024; d <<= 1) {
        int o = (t >= d) ? sc[t - d] : 0;
        __syncthreads();
        sc[t] += o;
        __syncthreads();
    }
    int excl = sc[t] - v;
    if (t < 512) {
        int c = (b << BSH) + t;
        if (c <= NN) offs[c] = base + excl;
        hist[t] = excl;
    }
    __syncthreads();
    for (int i = t; i < cnt; i += 1024) {
        unsigned w = in[i];
        int pos = atomicAdd(&hist[w >> 17], 1);
        srow[pos] = (int)(w & 0x1FFFFu);
    }
    __syncthreads();
    for (int i = t; i < cnt; i += 1024) ebuf[base + i] = srow[i];
}

// ---- wpack: W[384][40] f32 -> hi/lo bf16 B-fragments in MFMA lane order ----
__global__ __launch_bounds__(256) void wpack_kernel(const float* __restrict__ W,
                                                    unsigned short* __restrict__ wbf) {
    int idx = blockIdx.x * 256 + threadIdx.x;
    if (idx >= 12 * 3 * 2 * 64 * 8) return;
    int j    = idx & 7;
    int lane = (idx >> 3) & 63;
    int hl   = (idx >> 9) & 1;
    int rest = idx >> 10;          // kc*3 + t
    int t    = rest % 3;
    int kc   = rest / 3;
    int k = kc * 32 + 8 * (lane >> 4) + j;
    int c = 16 * t + (lane & 15);
    float w = (c < NCLS) ? W[k * NCLS + c] : 0.f;
    unsigned short hi = f2bf(w);
    wbf[idx] = (hl == 0) ? hi : f2bf(w - bf2f(hi));
}

// ---------------- h = concat(xE, logH, logS) @ W ; g = h * dinv (bf16 out) --
// Barrier-free, zero-LDS: each lane direct-loads its own A-row slices (the
// wave's 16 consecutive rows x 128 B per instruction pair -> coalesced; 2nd
// half L1-hit). x0 via 1 extra dword; dinv per-lane from int4 of offs.
// Waves are fully independent pipelines -> latency hidden by ILP, no
// block-wide barrier drain (the R14/R15 limiter).
__global__ __launch_bounds__(256) void h_kernel(
    const float* __restrict__ xE, const float* __restrict__ xH,
    const float* __restrict__ xS, const unsigned short* __restrict__ wbf,
    const int* __restrict__ offs, unsigned short* __restrict__ gbf) {

    int t = threadIdx.x;
    int lane = t & 63;
    int wv = t >> 6;                 // wave id 0..3
    int n0 = blockIdx.x * 64;
    int r  = lane & 15;              // A row / C col
    int kq = lane >> 4;              // k-quarter
    int myrow = n0 + 16 * wv + r;
    bool rowok = myrow < NN;

    f32x4 acc0 = {0.f, 0.f, 0.f, 0.f};
    f32x4 acc1 = acc0, acc2 = acc0;

    const bf16x8* wfr = reinterpret_cast<const bf16x8*>(wbf);

    for (int m = 0; m < 3; ++m) {
        const float* xb = (m == 0) ? xE : (m == 1) ? xH : xS;
        const float* xrow = xb + (size_t)myrow * DIM;

        // hoisted x loads: 8 float4s = this lane's 4 kc4-slices
        float4 xf[8];
#pragma unroll
        for (int kc4 = 0; kc4 < 4; ++kc4) {
            int off = kc4 * 32 + kq * 8;
            xf[2 * kc4]     = rowok ? *reinterpret_cast<const float4*>(xrow + off)
                                    : make_float4(0.f, 0.f, 0.f, 0.f);
            xf[2 * kc4 + 1] = rowok ? *reinterpret_cast<const float4*>(xrow + off + 4)
                                    : make_float4(0.f, 0.f, 0.f, 0.f);
        }

        float scm = 1.f;
        if (m > 0) {
            float x0 = rowok ? xrow[0] : 1.f;   // guard -> scm=0, no NaN
            if (m == 1) {
                scm = acoshf(fmaxf(x0, 1.f)) * rsqrtf(fmaxf(x0 * x0 - 1.f, EPSF));
            } else {
                float cc = fminf(fmaxf(x0, -1.f), 1.f);
                scm = acosf(cc) * rsqrtf(fmaxf(1.f - x0 * x0, EPSF));
            }
        }

#pragma unroll
        for (int kc4 = 0; kc4 < 4; ++kc4) {
            float4 f0 = xf[2 * kc4], f1 = xf[2 * kc4 + 1];
            float a[8] = {f0.x, f0.y, f0.z, f0.w, f1.x, f1.y, f1.z, f1.w};
            if (m > 0 && kc4 == 0 && kq == 0) a[0] = 0.f;   // logmap zeroes k=0

            bf16x8 ah, al;
#pragma unroll
            for (int j = 0; j < 8; ++j) {
                float av = a[j] * scm;
                unsigned short hbits = f2bf(av);
                ah[j] = (short)hbits;
                al[j] = (short)f2bf(av - bf2f(hbits));
            }

            int kc = m * 4 + kc4;
            const bf16x8* wb = wfr + (size_t)(kc * 3) * 2 * 64;
            bf16x8 bh0 = wb[0 * 128 + 0 * 64 + lane];
            bf16x8 bl0 = wb[0 * 128 + 1 * 64 + lane];
            bf16x8 bh1 = wb[1 * 128 + 0 * 64 + lane];
            bf16x8 bl1 = wb[1 * 128 + 1 * 64 + lane];
            bf16x8 bh2 = wb[2 * 128 + 0 * 64 + lane];
            bf16x8 bl2 = wb[2 * 128 + 1 * 64 + lane];

            acc0 = __builtin_amdgcn_mfma_f32_16x16x32_bf16(ah, bh0, acc0, 0, 0, 0);
            acc0 = __builtin_amdgcn_mfma_f32_16x16x32_bf16(al, bh0, acc0, 0, 0, 0);
            acc0 = __builtin_amdgcn_mfma_f32_16x16x32_bf16(ah, bl0, acc0, 0, 0, 0);
            acc1 = __builtin_amdgcn_mfma_f32_16x16x32_bf16(ah, bh1, acc1, 0, 0, 0);
            acc1 = __builtin_amdgcn_mfma_f32_16x16x32_bf16(al, bh1, acc1, 0, 0, 0);
            acc1 = __builtin_amdgcn_mfma_f32_16x16x32_bf16(ah, bl1, acc1, 0, 0, 0);
            acc2 = __builtin_amdgcn_mfma_f32_16x16x32_bf16(ah, bh2, acc2, 0, 0, 0);
            acc2 = __builtin_amdgcn_mfma_f32_16x16x32_bf16(al, bh2, acc2, 0, 0, 0);
            acc2 = __builtin_amdgcn_mfma_f32_16x16x32_bf16(ah, bl2, acc2, 0, 0, 0);
        }
    }

    // per-lane dinv for the 4 C rows this lane writes
    int nbase = n0 + 16 * wv + 4 * kq;     // multiple of 4
    int4 oa = make_int4(0, 0, 0, 0);
    int ob = 0;
    if (nbase < NN) {
        oa = *reinterpret_cast<const int4*>(offs + nbase);
        ob = offs[min(nbase + 4, NN)];
    }
    int dg[4] = {oa.y - oa.x, oa.z - oa.y, oa.w - oa.z, ob - oa.w};

    // C/D: node = nbase + i ; class = 16t + r   [m89 layout]
#pragma unroll
    for (int i = 0; i < 4; ++i) {
        int n = nbase + i;
        if (n < NN) {
            float di = rsqrtf((float)(dg[i] + 1));   // +1 self loop
            unsigned short* gr = gbf + (size_t)n * GSTR;
            gr[r]      = f2bf(acc0[i] * di);
            gr[16 + r] = f2bf(acc1[i] * di);
            if (r < 8)
                gr[32 + r] = f2bf(acc2[i] * di);
        }
    }
}

// ------ gather: bf16 g (128B-padded rows), 5 threads/node x bf16x8 ----------
__global__ __launch_bounds__(256) void gather_kernel(
    const int* __restrict__ offs, const int* __restrict__ ebuf,
    const unsigned short* __restrict__ gbf, float* __restrict__ out) {
    int t = blockIdx.x * blockDim.x + threadIdx.x;
    if (t >= NN * 5) return;
    int n  = t / 5;
    int c8 = t - n * 5;

    const u16x8* gb = reinterpret_cast<const u16x8*>(gbf) + c8;
    int s = offs[n], e = offs[n + 1];
    float dinv = rsqrtf((float)(e - s + 1));

    u16x8 sv = gb[n * 8];            // self loop (dinv[n] folded in g)
    float a0[8], a1[8];
#pragma unroll
    for (int k = 0; k < 8; ++k) { a0[k] = bf2f(sv[k]); a1[k] = 0.f; }

    int j = s;
    for (; j + 1 < e; j += 2) {
        int r0 = ebuf[j], r1 = ebuf[j + 1];
        u16x8 v0 = gb[r0 * 8];
        u16x8 v1 = gb[r1 * 8];
#pragma unroll
        for (int k = 0; k < 8; ++k) { a0[k] += bf2f(v0[k]); a1[k] += bf2f(v1[k]); }
    }
    if (j < e) {
        u16x8 v = gb[ebuf[j] * 8];
#pragma unroll
        for (int k = 0; k < 8; ++k) a0[k] += bf2f(v[k]);
    }

    float* on = out + (size_t)n * NCLS + c8 * 8;
    float4 o0, o1;
    o0.x = (a0[0] + a1[0]) * dinv;
    o0.y = (a0[1] + a1[1]) * dinv;
    o0.z = (a0[2] + a1[2]) * dinv;
    o0.w = (a0[3] + a1[3]) * dinv;
    o1.x = (a0[4] + a1[4]) * dinv;
    o1.y = (a0[5] + a1[5]) * dinv;
    o1.z = (a0[6] + a1[6]) * dinv;
    o1.w = (a0[7] + a1[7]) * dinv;
    *reinterpret_cast<float4*>(on)     = o0;
    *reinterpret_cast<float4*>(on + 4) = o1;
}

extern "C" void kernel_launch(void* const* d_in, const int* in_sizes, int n_in,
                              void* d_out, int out_size, void* d_ws, size_t ws_size,
                              hipStream_t stream) {
    const float* xE = (const float*)d_in[0];
    const float* xH = (const float*)d_in[1];
    const float* xS = (const float*)d_in[2];
    const float* W  = (const float*)d_in[3];
    const int*   ei = (const int*)d_in[4];
    const int* row = ei;            // edge_index[0]
    const int* col = ei + NE;       // edge_index[1]
    float* out = (float*)d_out;

    auto pad = [](size_t x) { return (x + 255) & ~(size_t)255; };
    char* p = (char*)d_ws;
    int* gcur  = (int*)p;               p += pad((size_t)NBKT * 4);
    int* bbase = (int*)p;               p += pad((size_t)NBKT * 4);
    int* offs  = (int*)p;               p += pad((size_t)(NN + 1) * 4);
    int* ebuf  = (int*)p;               p += pad((size_t)NE * 4);
    // pairs (NBKT*CAP*4 = 14.45 MB) aliases gbf (12.8 MB): pairs dead after
    // binB; gbf written by h afterwards.
    unsigned* pairs = (unsigned*)p;
    unsigned short* gbf = (unsigned short*)p;
    p += pad((size_t)NBKT * CAP * 4);
    unsigned short* wbf = (unsigned short*)p;   // 147456 B

    hipMemsetAsync(gcur, 0, (size_t)NBKT * 4, stream);

    wpack_kernel<<<(12 * 3 * 2 * 64 * 8 + 255) / 256, 256, 0, stream>>>(W, wbf);
    binA_kernel<<<ABLK, 256, 0, stream>>>(row, col, gcur, pairs);
    bscan_kernel<<<1, 256, 0, stream>>>(gcur, bbase);
    binB_kernel<<<NBKT, 1024, 0, stream>>>(gcur, bbase, pairs, ebuf, offs);
    h_kernel<<<(NN + 63) / 64, 256, 0, stream>>>(xE, xH, xS, wbf, offs, gbf);
    gather_kernel<<<(NN * 5 + 255) / 256, 256, 0, stream>>>(offs, ebuf, gbf, out);
}